// Round 5
// baseline (122.517 us; speedup 1.0000x reference)
//
#include <hip/hip_runtime.h>
#include <hip/hip_cooperative_groups.h>

namespace cg = cooperative_groups;

// ObliviousDecisionLayer on MI355X — single fused cooperative kernel.
// decisions[b,t,d] = rowsum(inputs)[b] * rowsum(dw)[t,d]  (einsum shares no index)
// Leaf fold: bit d of leaf index: 0 -> dec[d], 1 -> 1-dec[d]; mean folded into leaf scale.
//
// R5: fuse prep+forest via hipLaunchCooperativeKernel + this_grid().sync().
// Removes one dispatch boundary and the prep-tail serialization; BPB 8->16
// halves per-block table re-read traffic (39 MB -> 19.5 MB, L3-resident).

#define NUM_TREES 256
#define DEPTH 6
#define LEAVES 64
#define BATCH 4096
#define FEATURES 256
#define BPB 16
#define NBLK (BATCH / BPB)                  // 256 blocks = 1/CU
#define NWAVE (NBLK * 4)                    // 1024 waves
#define NROWS (BATCH + NUM_TREES * DEPTH)   // 5632 row-sum tasks

// ws layout (floats):
#define WS_SIN  0        // [4096]
#define WS_SWT  4096     // [6][256]  sw_t[d][t]
#define WS_THT  5632     // [6][256]  th_t[d][t]
#define WS_B5   7168     // [8][256] float4: B5[c][t] = leaf4[t][c+8] / 256
#define WS_D5   15360    // [8][256] float4: D5[c][t] = (leaf4[t][c]-leaf4[t][c+8]) / 256

__global__ __launch_bounds__(256, 1) void fused_kernel(
    const float* __restrict__ inputs,   // [4096][256]
    const float* __restrict__ dw,       // [1536][256]
    const float* __restrict__ thr,      // [256][6]
    const float* __restrict__ leaf,     // [256][64]
    float* __restrict__ ws,
    float* __restrict__ out)            // [4096]
{
    const int tid  = threadIdx.x;
    const int lane = tid & 63;
    const int wv   = tid >> 6;
    const int wg   = blockIdx.x * 4 + wv;   // global wave id, 0..1023
    const float scale = 1.0f / (float)NUM_TREES;

    // ================= Phase 1: row sums + table transposes =================
    // Extra tasks (issued first so loads overlap the rowsum loads):
    //   wg  0..31 : leaf pre-fold, chunk c=wg>>2, trees t=(wg&3)*64+lane
    //   wg 32..55 : threshold transpose, idx=(wg-32)*64+lane
    float4 va, vb;
    float thval = 0.0f;
    int lf_c = 0, lf_t = 0, th_idx = 0;
    if (wg < 32) {
        lf_c = wg >> 2;
        lf_t = ((wg & 3) << 6) | lane;
        const float4* lp = reinterpret_cast<const float4*>(leaf);
        va = lp[lf_t * (LEAVES / 4) + lf_c];
        vb = lp[lf_t * (LEAVES / 4) + lf_c + 8];
    } else if (wg < 56) {
        th_idx = (wg - 32) * 64 + lane;     // 0..1535 = t*6+d
        thval = thr[th_idx];
    }

    // Row-sum loads, 6-deep ILP (tasks wg + k*1024; k=0..4 always valid)
#define ROWPTR(task) ((task) < BATCH ? inputs + (size_t)(task) * FEATURES \
                                     : dw + (size_t)((task) - BATCH) * FEATURES)
    const float4 r0 = reinterpret_cast<const float4*>(ROWPTR(wg            ))[lane];
    const float4 r1 = reinterpret_cast<const float4*>(ROWPTR(wg + 1 * NWAVE))[lane];
    const float4 r2 = reinterpret_cast<const float4*>(ROWPTR(wg + 2 * NWAVE))[lane];
    const float4 r3 = reinterpret_cast<const float4*>(ROWPTR(wg + 3 * NWAVE))[lane];
    const float4 r4 = reinterpret_cast<const float4*>(ROWPTR(wg + 4 * NWAVE))[lane];
    const bool has5 = (wg + 5 * NWAVE) < NROWS;       // wg < 512
    float4 r5;
    if (has5) r5 = reinterpret_cast<const float4*>(ROWPTR(wg + 5 * NWAVE))[lane];

    // Finish extra tasks
    if (wg < 32) {
        float4 d, b;
        d.x = (va.x - vb.x) * scale; d.y = (va.y - vb.y) * scale;
        d.z = (va.z - vb.z) * scale; d.w = (va.w - vb.w) * scale;
        b.x = vb.x * scale; b.y = vb.y * scale;
        b.z = vb.z * scale; b.w = vb.w * scale;
        reinterpret_cast<float4*>(ws + WS_D5)[lf_c * NUM_TREES + lf_t] = d;
        reinterpret_cast<float4*>(ws + WS_B5)[lf_c * NUM_TREES + lf_t] = b;
    } else if (wg < 56) {
        const int t = th_idx / DEPTH;
        const int d = th_idx - t * DEPTH;
        ws[WS_THT + d * NUM_TREES + t] = thval;
    }

    // Reduce + scatter each row sum
    auto reduce_store = [&](float4 v, int task) {
        float s = (v.x + v.y) + (v.z + v.w);
#pragma unroll
        for (int off = 32; off > 0; off >>= 1)
            s += __shfl_down(s, off);
        if (lane == 0) {
            if (task < BATCH) {
                ws[WS_SIN + task] = s;
            } else {
                const int r = task - BATCH;       // = t*6 + d
                const int t = r / DEPTH;
                const int d = r - t * DEPTH;
                ws[WS_SWT + d * NUM_TREES + t] = s;
            }
        }
    };
    reduce_store(r0, wg);
    reduce_store(r1, wg + 1 * NWAVE);
    reduce_store(r2, wg + 2 * NWAVE);
    reduce_store(r3, wg + 3 * NWAVE);
    reduce_store(r4, wg + 4 * NWAVE);
    if (has5) reduce_store(r5, wg + 5 * NWAVE);

    __threadfence();
    cg::this_grid().sync();

    // ================= Phase 2: per-(b,t) evaluation + tree-mean =================
    const int t  = tid;                 // tree index 0..255
    const int b0 = blockIdx.x * BPB;

    float sw[DEPTH], th[DEPTH];
#pragma unroll
    for (int d = 0; d < DEPTH; ++d) {
        sw[d] = ws[WS_SWT + d * NUM_TREES + t];
        th[d] = ws[WS_THT + d * NUM_TREES + t];
    }
    float b5[32], d5[32];
#pragma unroll
    for (int c = 0; c < 8; ++c) {
        float4 vbv = reinterpret_cast<const float4*>(ws + WS_B5)[c * NUM_TREES + t];
        float4 vdv = reinterpret_cast<const float4*>(ws + WS_D5)[c * NUM_TREES + t];
        b5[4 * c + 0] = vbv.x; b5[4 * c + 1] = vbv.y;
        b5[4 * c + 2] = vbv.z; b5[4 * c + 3] = vbv.w;
        d5[4 * c + 0] = vdv.x; d5[4 * c + 1] = vdv.y;
        d5[4 * c + 2] = vdv.z; d5[4 * c + 3] = vdv.w;
    }

    float res[BPB];
#pragma unroll
    for (int bi = 0; bi < BPB; ++bi) {
        const float si = ws[WS_SIN + b0 + bi];   // block-uniform
        float dec[DEPTH];
#pragma unroll
        for (int d = 0; d < DEPTH; ++d) {
            const float x = fmaf(si, sw[d], th[d]);
            dec[d] = 1.0f / (1.0f + __expf(-x)); // sigmoid
        }
        float m[32];
#pragma unroll
        for (int i = 0; i < 32; ++i) m[i] = fmaf(dec[5], d5[i], b5[i]);
#pragma unroll
        for (int i = 0; i < 16; ++i) m[i] = fmaf(dec[4], m[i] - m[i + 16], m[i + 16]);
#pragma unroll
        for (int i = 0; i < 8; ++i)  m[i] = fmaf(dec[3], m[i] - m[i + 8],  m[i + 8]);
#pragma unroll
        for (int i = 0; i < 4; ++i)  m[i] = fmaf(dec[2], m[i] - m[i + 4],  m[i + 4]);
#pragma unroll
        for (int i = 0; i < 2; ++i)  m[i] = fmaf(dec[1], m[i] - m[i + 2],  m[i + 2]);
        res[bi] = fmaf(dec[0], m[0] - m[1], m[1]);
    }

    // Reduce over 256 trees (4 waves); 1/256 already folded into leaves
    __shared__ float red[4][BPB];
#pragma unroll
    for (int bi = 0; bi < BPB; ++bi) {
        float v = res[bi];
#pragma unroll
        for (int off = 32; off > 0; off >>= 1)
            v += __shfl_down(v, off);
        if (lane == 0) red[wv][bi] = v;
    }
    __syncthreads();
    if (tid < BPB) {
        out[b0 + tid] = red[0][tid] + red[1][tid] + red[2][tid] + red[3][tid];
    }
}

extern "C" void kernel_launch(void* const* d_in, const int* in_sizes, int n_in,
                              void* d_out, int out_size, void* d_ws, size_t ws_size,
                              hipStream_t stream) {
    const float* inputs = (const float*)d_in[0];
    const float* dw     = (const float*)d_in[1];
    const float* thr    = (const float*)d_in[2];
    const float* leaf   = (const float*)d_in[3];
    float* out = (float*)d_out;
    float* ws  = (float*)d_ws;

    void* args[] = {(void*)&inputs, (void*)&dw, (void*)&thr, (void*)&leaf,
                    (void*)&ws, (void*)&out};
    hipLaunchCooperativeKernel((void*)fused_kernel, dim3(NBLK), dim3(256),
                               args, 0, stream);
}

// Round 6
// 68.885 us; speedup vs baseline: 1.7786x; 1.7786x over previous
//
#include <hip/hip_runtime.h>
#include <hip/hip_bf16.h>

// ObliviousDecisionLayer on MI355X — two-kernel (R4 structure), R6 tuning.
// decisions[b,t,d] = rowsum(inputs)[b] * rowsum(dw)[t,d]  (einsum shares no index).
// Leaf fold: bit d of leaf index: 0 -> dec[d], 1 -> 1-dec[d]; /256 folded into leaves.
//
// R6 changes vs R4:
//  - sigmoid uses v_rcp_f32 (__builtin_amdgcn_rcpf) instead of exact f32 div
//    (no -ffast-math -> 1/(1+e) was a ~9-instr div sequence x48/thread).
//  - forest row-sums its own 8 input rows inline (coalesced, each row read once
//    grid-wide) -> prep loses 4096 waves and the s_in ws round-trip.
//  - R5 lesson: cooperative grid.sync costs ~30+ us on 256 blocks; stream
//    ordering between two launches is far cheaper. Do not re-fuse.

#define NUM_TREES 256
#define DEPTH 6
#define LEAVES 64
#define BATCH 4096
#define FEATURES 256
#define BPB 8  // batch rows per forest block

// ws layout (floats):
#define WS_SWT  0        // [6][256]  sw_t[d][t] = rowsum(dw[t][d][:])
#define WS_THT  1536     // [6][256]  th_t[d][t] = thr[t][d]
#define WS_B5   3072     // [8][256] float4: B5[c][t] = leaf4[t][c+8] / 256
#define WS_D5   11264    // [8][256] float4: D5[c][t] = (leaf4[t][c]-leaf4[t][c+8]) / 256

// ---------------- Kernel 1: dw row sums + table transposes ----------------
// waves 0..1535   : r=gw (=t*6+d): sw_t[d][t] = sum_k dw[r][k]
// waves 1536..1599: leaf pre-fold (float4 chunks)
// waves 1600..1623: threshold transpose
__global__ __launch_bounds__(256) void prep_kernel(
    const float* __restrict__ dw,       // [1536][256]
    const float* __restrict__ thr,      // [256][6]
    const float* __restrict__ leaf,     // [256][64]
    float* __restrict__ ws)
{
    const int gw   = (blockIdx.x * blockDim.x + threadIdx.x) >> 6;
    const int lane = threadIdx.x & 63;
    const float scale = 1.0f / (float)NUM_TREES;

    if (gw < NUM_TREES * DEPTH) {
        const int t = gw / DEPTH;
        const int d = gw - t * DEPTH;
        float4 v = reinterpret_cast<const float4*>(dw + (size_t)gw * FEATURES)[lane];
        float s = (v.x + v.y) + (v.z + v.w);
#pragma unroll
        for (int off = 32; off > 0; off >>= 1)
            s += __shfl_down(s, off);
        if (lane == 0) ws[WS_SWT + d * NUM_TREES + t] = s;
    } else if (gw < NUM_TREES * DEPTH + 64) {
        // leaf pre-fold: wave j -> chunk c=j>>2 (0..15), trees t=(j&3)*64+lane
        const int j = gw - NUM_TREES * DEPTH;
        const int c = j >> 2;
        const int t = ((j & 3) << 6) | lane;
        const float4* lp = reinterpret_cast<const float4*>(leaf);
        if (c < 8) {
            float4 va = lp[t * (LEAVES / 4) + c];
            float4 vb = lp[t * (LEAVES / 4) + c + 8];
            float4 d;
            d.x = (va.x - vb.x) * scale; d.y = (va.y - vb.y) * scale;
            d.z = (va.z - vb.z) * scale; d.w = (va.w - vb.w) * scale;
            reinterpret_cast<float4*>(ws + WS_D5)[c * NUM_TREES + t] = d;
        } else {
            float4 vb = lp[t * (LEAVES / 4) + c];
            float4 b;
            b.x = vb.x * scale; b.y = vb.y * scale;
            b.z = vb.z * scale; b.w = vb.w * scale;
            reinterpret_cast<float4*>(ws + WS_B5)[(c - 8) * NUM_TREES + t] = b;
        }
    } else {
        // threshold transpose: 24 waves cover 1536 elements
        const int j = gw - (NUM_TREES * DEPTH + 64);
        const int idx = j * 64 + lane;       // = t*6 + d
        const int t = idx / DEPTH;
        const int d = idx - t * DEPTH;
        ws[WS_THT + d * NUM_TREES + t] = thr[idx];
    }
}

// ---------------- Kernel 2: inline row-sums + evaluation + tree-mean ----------------
__global__ __launch_bounds__(256, 1) void forest_kernel(
    const float* __restrict__ inputs,   // [4096][256]
    const float* __restrict__ ws,
    float* __restrict__ out)            // [4096]
{
    const int tid  = threadIdx.x;       // tree index 0..255
    const int lane = tid & 63;
    const int wv   = tid >> 6;
    const int b0   = blockIdx.x * BPB;

    // --- issue all loads up front for ILP ---
    // own-block input rows: wave wv handles rows b0+2wv, b0+2wv+1
    const float4* ip = reinterpret_cast<const float4*>(inputs);
    const float4 a0 = ip[(size_t)(b0 + 2 * wv)     * (FEATURES / 4) + lane];
    const float4 a1 = ip[(size_t)(b0 + 2 * wv + 1) * (FEATURES / 4) + lane];

    // per-tree tables (stride-1 in t, coalesced)
    const int t = tid;
    float sw[DEPTH], th[DEPTH];
#pragma unroll
    for (int d = 0; d < DEPTH; ++d) {
        sw[d] = ws[WS_SWT + d * NUM_TREES + t];
        th[d] = ws[WS_THT + d * NUM_TREES + t];
    }
    float b5[32], d5[32];
#pragma unroll
    for (int c = 0; c < 8; ++c) {
        float4 vb = reinterpret_cast<const float4*>(ws + WS_B5)[c * NUM_TREES + t];
        float4 vd = reinterpret_cast<const float4*>(ws + WS_D5)[c * NUM_TREES + t];
        b5[4 * c + 0] = vb.x; b5[4 * c + 1] = vb.y;
        b5[4 * c + 2] = vb.z; b5[4 * c + 3] = vb.w;
        d5[4 * c + 0] = vd.x; d5[4 * c + 1] = vd.y;
        d5[4 * c + 2] = vd.z; d5[4 * c + 3] = vd.w;
    }

    // --- row sums -> LDS broadcast ---
    float s0 = (a0.x + a0.y) + (a0.z + a0.w);
    float s1 = (a1.x + a1.y) + (a1.z + a1.w);
#pragma unroll
    for (int off = 32; off > 0; off >>= 1) {
        s0 += __shfl_down(s0, off);
        s1 += __shfl_down(s1, off);
    }
    __shared__ float sib[BPB];
    if (lane == 0) { sib[2 * wv] = s0; sib[2 * wv + 1] = s1; }
    __syncthreads();

    // --- evaluate BPB rows ---
    float res[BPB];
#pragma unroll
    for (int bi = 0; bi < BPB; ++bi) {
        const float si = sib[bi];            // LDS broadcast (same addr, no conflict)
        float dec[DEPTH];
#pragma unroll
        for (int d = 0; d < DEPTH; ++d) {
            const float x = fmaf(si, sw[d], th[d]);
            // sigmoid via v_exp + v_rcp (~1 ulp; exact div is ~9 instrs w/o fast-math)
            dec[d] = __builtin_amdgcn_rcpf(1.0f + __expf(-x));
        }
        float m[32];
#pragma unroll
        for (int i = 0; i < 32; ++i) m[i] = fmaf(dec[5], d5[i], b5[i]);
#pragma unroll
        for (int i = 0; i < 16; ++i) m[i] = fmaf(dec[4], m[i] - m[i + 16], m[i + 16]);
#pragma unroll
        for (int i = 0; i < 8; ++i)  m[i] = fmaf(dec[3], m[i] - m[i + 8],  m[i + 8]);
#pragma unroll
        for (int i = 0; i < 4; ++i)  m[i] = fmaf(dec[2], m[i] - m[i + 4],  m[i + 4]);
#pragma unroll
        for (int i = 0; i < 2; ++i)  m[i] = fmaf(dec[1], m[i] - m[i + 2],  m[i + 2]);
        res[bi] = fmaf(dec[0], m[0] - m[1], m[1]);
    }

    // --- reduce over 256 trees (4 waves); 1/256 pre-folded into leaves ---
    __shared__ float red[4][BPB];
#pragma unroll
    for (int bi = 0; bi < BPB; ++bi) {
        float v = res[bi];
#pragma unroll
        for (int off = 32; off > 0; off >>= 1)
            v += __shfl_down(v, off);
        if (lane == 0) red[wv][bi] = v;
    }
    __syncthreads();
    if (tid < BPB) {
        out[b0 + tid] = red[0][tid] + red[1][tid] + red[2][tid] + red[3][tid];
    }
}

extern "C" void kernel_launch(void* const* d_in, const int* in_sizes, int n_in,
                              void* d_out, int out_size, void* d_ws, size_t ws_size,
                              hipStream_t stream) {
    const float* inputs = (const float*)d_in[0];  // [4096][256]
    const float* dw     = (const float*)d_in[1];  // [256][6][256]
    const float* thr    = (const float*)d_in[2];  // [256][6]
    const float* leaf   = (const float*)d_in[3];  // [256][64]
    float* out = (float*)d_out;                   // [4096]
    float* ws  = (float*)d_ws;

    // prep: 1536 + 64 + 24 = 1624 waves, 4 waves/block -> 406 blocks
    prep_kernel<<<406, 256, 0, stream>>>(dw, thr, leaf, ws);

    // forest: 4096 / BPB = 512 blocks of 256 threads
    forest_kernel<<<BATCH / BPB, 256, 0, stream>>>(inputs, ws, out);
}